// Round 1
// baseline (531.378 us; speedup 1.0000x reference)
//
#include <hip/hip_runtime.h>

#define BATCH 16
#define NPIX  4096
#define CCH   512
#define KP    40   // padded LDS k-stride (bf16 elems)

using bf16x8   = __attribute__((ext_vector_type(8))) __bf16;
using floatx4  = __attribute__((ext_vector_type(4))) float;
using ushort8v = __attribute__((ext_vector_type(8))) unsigned short;

static __device__ __forceinline__ unsigned short f2bf(float f) {
    unsigned u = __builtin_bit_cast(unsigned, f);
    unsigned r = 0x7fffu + ((u >> 16) & 1u);   // round-to-nearest-even
    return (unsigned short)((u + r) >> 16);
}

static __device__ __forceinline__ bf16x8 ld_frag(const unsigned short* p) {
    return __builtin_bit_cast(bf16x8, *(const ushort8v*)p);
}

// ---------------------------------------------------------------------------
// Kernel 1: S[b][i][j] = sum_n A[b][n][i] * A[b][n][j]
// 128x128 output tile per block, BK=32. LDS tiles stored [chan][n] (transposed)
// so MFMA fragments (k = n contiguous) are ds_read_b128.
// ---------------------------------------------------------------------------
__global__ __launch_bounds__(256) void k_ata(const float* __restrict__ A,
                                             float* __restrict__ S) {
    __shared__ unsigned short sA[128 * KP];
    __shared__ unsigned short sB[128 * KP];
    const int bi = blockIdx.x, bj = blockIdx.y, b = blockIdx.z;
    const float* __restrict__ pa = A + (size_t)b * NPIX * CCH + bi * 128;
    const float* __restrict__ pb = A + (size_t)b * NPIX * CCH + bj * 128;
    const int tid  = threadIdx.x;
    const int lane = tid & 63;
    const int wave = tid >> 6;

    floatx4 acc[2][8];
#pragma unroll
    for (int tm = 0; tm < 2; ++tm)
#pragma unroll
        for (int tn = 0; tn < 8; ++tn)
            acc[tm][tn] = floatx4{0.f, 0.f, 0.f, 0.f};

    for (int k0 = 0; k0 < NPIX; k0 += 32) {
        // Stage two 32(n) x 128(ch) fp32 tiles, transposed to [ch][n] bf16.
#pragma unroll
        for (int r = 0; r < 2; ++r) {
            int idx = tid + 256 * r;            // 0..511
            int n   = (idx >> 5) * 2;           // even row 0..30
            int c4  = (idx & 31) * 4;           // 0..124
            const float4 a0 = *(const float4*)(pa + (size_t)(k0 + n)     * CCH + c4);
            const float4 a1 = *(const float4*)(pa + (size_t)(k0 + n + 1) * CCH + c4);
            const float4 b0 = *(const float4*)(pb + (size_t)(k0 + n)     * CCH + c4);
            const float4 b1 = *(const float4*)(pb + (size_t)(k0 + n + 1) * CCH + c4);
            const float* a0p = (const float*)&a0;
            const float* a1p = (const float*)&a1;
            const float* b0p = (const float*)&b0;
            const float* b1p = (const float*)&b1;
#pragma unroll
            for (int d = 0; d < 4; ++d) {
                unsigned va = (unsigned)f2bf(a0p[d]) | ((unsigned)f2bf(a1p[d]) << 16);
                unsigned vb = (unsigned)f2bf(b0p[d]) | ((unsigned)f2bf(b1p[d]) << 16);
                *(unsigned*)&sA[(c4 + d) * KP + n] = va;   // n even -> 4B aligned
                *(unsigned*)&sB[(c4 + d) * KP + n] = vb;
            }
        }
        __syncthreads();

        const int kq = (lane >> 4) * 8;
        bf16x8 af[2], bfv[8];
#pragma unroll
        for (int tm = 0; tm < 2; ++tm)
            af[tm] = ld_frag(&sA[(wave * 32 + tm * 16 + (lane & 15)) * KP + kq]);
#pragma unroll
        for (int tn = 0; tn < 8; ++tn)
            bfv[tn] = ld_frag(&sB[(tn * 16 + (lane & 15)) * KP + kq]);
#pragma unroll
        for (int tm = 0; tm < 2; ++tm)
#pragma unroll
            for (int tn = 0; tn < 8; ++tn)
                acc[tm][tn] = __builtin_amdgcn_mfma_f32_16x16x32_bf16(
                    af[tm], bfv[tn], acc[tm][tn], 0, 0, 0);
        __syncthreads();
    }

    // Epilogue: D row = (lane>>4)*4 + reg (i), col = lane&15 (j)
    float* Sb = S + ((size_t)b * CCH + bi * 128) * CCH + bj * 128;
#pragma unroll
    for (int tm = 0; tm < 2; ++tm)
#pragma unroll
        for (int tn = 0; tn < 8; ++tn)
#pragma unroll
            for (int r = 0; r < 4; ++r) {
                int irow = wave * 32 + tm * 16 + (lane >> 4) * 4 + r;
                int jcol = tn * 16 + (lane & 15);
                Sb[(size_t)irow * CCH + jcol] = acc[tm][tn][r];
            }
}

// ---------------------------------------------------------------------------
// Kernel 2: row softmax of S (fp32) -> attn (bf16). One block per row.
// ---------------------------------------------------------------------------
__global__ __launch_bounds__(256) void k_softmax(const float* __restrict__ S,
                                                 unsigned short* __restrict__ P) {
    __shared__ float red[6];
    const size_t row = blockIdx.x;
    const float* p = S + row * CCH;
    const int tid = threadIdx.x, lane = tid & 63, wave = tid >> 6;

    float x0 = p[tid], x1 = p[tid + 256];
    float m = fmaxf(x0, x1);
#pragma unroll
    for (int o = 32; o; o >>= 1) m = fmaxf(m, __shfl_xor(m, o, 64));
    if (lane == 0) red[wave] = m;
    __syncthreads();
    if (tid == 0) red[4] = fmaxf(fmaxf(red[0], red[1]), fmaxf(red[2], red[3]));
    __syncthreads();
    m = red[4];

    float e0 = __expf(x0 - m), e1 = __expf(x1 - m);
    float s = e0 + e1;
#pragma unroll
    for (int o = 32; o; o >>= 1) s += __shfl_xor(s, o, 64);
    if (lane == 0) red[wave] = s;
    __syncthreads();
    if (tid == 0) red[5] = red[0] + red[1] + red[2] + red[3];
    __syncthreads();
    float inv = 1.0f / red[5];

    P[row * CCH + tid]       = f2bf(e0 * inv);
    P[row * CCH + tid + 256] = f2bf(e1 * inv);
}

// ---------------------------------------------------------------------------
// Kernel 3: out[b][n][i] = gamma * sum_j attn[b][i][j]*A[b][n][j] + in[b][n][i]
// 128(n) x 128(i) tile, BK=32 over j. Both LDS layouts are k-contiguous.
// ---------------------------------------------------------------------------
__global__ __launch_bounds__(256) void k_av(const float* __restrict__ A,
                                            const unsigned short* __restrict__ P,
                                            const float* __restrict__ gamma,
                                            float* __restrict__ out) {
    __shared__ unsigned short sA[128 * KP];   // [n][j]
    __shared__ unsigned short sB[128 * KP];   // [i][j]
    const int bn = blockIdx.x, bi = blockIdx.y, b = blockIdx.z;
    const float* __restrict__ Ab = A + ((size_t)b * NPIX + bn * 128) * CCH;
    const unsigned short* __restrict__ Pb = P + ((size_t)b * CCH + bi * 128) * CCH;
    const int tid = threadIdx.x, lane = tid & 63, wave = tid >> 6;
    const float g = gamma[0];

    floatx4 acc[2][8];
#pragma unroll
    for (int tm = 0; tm < 2; ++tm)
#pragma unroll
        for (int tn = 0; tn < 8; ++tn)
            acc[tm][tn] = floatx4{0.f, 0.f, 0.f, 0.f};

    for (int k0 = 0; k0 < CCH; k0 += 32) {
        // Stage A: 128(n) x 32(j) fp32 -> bf16, natural layout.
#pragma unroll
        for (int r = 0; r < 4; ++r) {
            int idx = tid + 256 * r;        // 0..1023
            int n   = idx >> 3;             // 0..127
            int j4  = (idx & 7) * 4;        // 0..28
            const float4 v = *(const float4*)(Ab + (size_t)n * CCH + k0 + j4);
            uint2 w;
            w.x = (unsigned)f2bf(v.x) | ((unsigned)f2bf(v.y) << 16);
            w.y = (unsigned)f2bf(v.z) | ((unsigned)f2bf(v.w) << 16);
            *(uint2*)&sA[n * KP + j4] = w;
        }
        // Stage B: 128(i) x 32(j) bf16, 16B loads/stores.
#pragma unroll
        for (int r = 0; r < 2; ++r) {
            int idx = tid + 256 * r;        // 0..511
            int i   = idx >> 2;             // 0..127
            int jo  = (idx & 3) * 8;        // 0,8,16,24
            ushort8v v = *(const ushort8v*)(Pb + (size_t)i * CCH + k0 + jo);
            *(ushort8v*)&sB[i * KP + jo] = v;
        }
        __syncthreads();

        const int kq = (lane >> 4) * 8;
        bf16x8 af[2], bfv[8];
#pragma unroll
        for (int tm = 0; tm < 2; ++tm)
            af[tm] = ld_frag(&sA[(wave * 32 + tm * 16 + (lane & 15)) * KP + kq]);
#pragma unroll
        for (int tn = 0; tn < 8; ++tn)
            bfv[tn] = ld_frag(&sB[(tn * 16 + (lane & 15)) * KP + kq]);
#pragma unroll
        for (int tm = 0; tm < 2; ++tm)
#pragma unroll
            for (int tn = 0; tn < 8; ++tn)
                acc[tm][tn] = __builtin_amdgcn_mfma_f32_16x16x32_bf16(
                    af[tm], bfv[tn], acc[tm][tn], 0, 0, 0);
        __syncthreads();
    }

    // Fused epilogue: out = g * acc + in (fp32, exact when g == 0)
    float* Ob = out + ((size_t)b * NPIX + bn * 128) * CCH + bi * 128;
    const float* Ib = A + ((size_t)b * NPIX + bn * 128) * CCH + bi * 128;
#pragma unroll
    for (int tm = 0; tm < 2; ++tm)
#pragma unroll
        for (int tn = 0; tn < 8; ++tn)
#pragma unroll
            for (int r = 0; r < 4; ++r) {
                int nrow = wave * 32 + tm * 16 + (lane >> 4) * 4 + r;
                int icol = tn * 16 + (lane & 15);
                size_t o = (size_t)nrow * CCH + icol;
                Ob[o] = g * acc[tm][tn][r] + Ib[o];
            }
}

// ---------------------------------------------------------------------------
extern "C" void kernel_launch(void* const* d_in, const int* in_sizes, int n_in,
                              void* d_out, int out_size, void* d_ws, size_t ws_size,
                              hipStream_t stream) {
    const float* inp   = (const float*)d_in[0];
    const float* gamma = (const float*)d_in[1];
    float* out = (float*)d_out;

    float* aTa = (float*)d_ws;                                    // 16*512*512 fp32 = 16.8 MB
    unsigned short* attn =
        (unsigned short*)((char*)d_ws + (size_t)BATCH * CCH * CCH * sizeof(float)); // 8.4 MB

    k_ata<<<dim3(4, 4, BATCH), 256, 0, stream>>>(inp, aTa);
    k_softmax<<<BATCH * CCH, 256, 0, stream>>>(aTa, attn);
    k_av<<<dim3(NPIX / 128, CCH / 128, BATCH), 256, 0, stream>>>(inp, attn, gamma, out);
}

// Round 2
// 458.991 us; speedup vs baseline: 1.1577x; 1.1577x over previous
//
#include <hip/hip_runtime.h>

#define BATCH 16
#define NPIX  4096
#define CCH   512
#define NSPLIT 4        // split-K for k_ata
#define KSPL  (NPIX / NSPLIT)   // 1024

using bf16x8   = __attribute__((ext_vector_type(8))) __bf16;
using floatx4  = __attribute__((ext_vector_type(4))) float;
using ushort8v = __attribute__((ext_vector_type(8))) unsigned short;

static __device__ __forceinline__ unsigned short f2bf(float f) {
    unsigned u = __builtin_bit_cast(unsigned, f);
    unsigned r = 0x7fffu + ((u >> 16) & 1u);   // round-to-nearest-even
    return (unsigned short)((u + r) >> 16);
}

static __device__ __forceinline__ bf16x8 ld_frag(const unsigned short* p) {
    return __builtin_bit_cast(bf16x8, *(const ushort8v*)p);
}

// async global->LDS, 16B per lane; LDS dest = wave-uniform base + lane*16
static __device__ __forceinline__ void gld16(const unsigned short* g, unsigned short* l) {
    __builtin_amdgcn_global_load_lds(
        (const __attribute__((address_space(1))) void*)g,
        (__attribute__((address_space(3))) void*)l,
        16, 0, 0);
}

// ---------------------------------------------------------------------------
// Kernel 0: fp32 [b][n][c] -> bf16 A_bf [b][n][c]  AND  bf16 A_T [b][c][n]
// 64x64 tile per block, LDS transpose for A_T.
// ---------------------------------------------------------------------------
__global__ __launch_bounds__(256) void k_cvt(const float* __restrict__ inp,
                                             unsigned short* __restrict__ Abf,
                                             unsigned short* __restrict__ AT) {
    __shared__ unsigned short sN[64 * 68];   // [n][c], pitch 68 shorts
    const int bn = blockIdx.x;   // 0..63  (n tile)
    const int bc = blockIdx.y;   // 0..7   (c tile)
    const int b  = blockIdx.z;
    const int t  = threadIdx.x;
    const int n0 = bn * 64, c0 = bc * 64;
    const float* ip = inp + ((size_t)b * NPIX + n0) * CCH + c0;
    unsigned short* op = Abf + ((size_t)b * NPIX + n0) * CCH + c0;

#pragma unroll
    for (int r = 0; r < 4; ++r) {
        int n  = r * 16 + (t >> 4);
        int c4 = (t & 15) * 4;
        float4 v = *(const float4*)(ip + (size_t)n * CCH + c4);
        uint2 w;
        w.x = (unsigned)f2bf(v.x) | ((unsigned)f2bf(v.y) << 16);
        w.y = (unsigned)f2bf(v.z) | ((unsigned)f2bf(v.w) << 16);
        *(uint2*)(op + (size_t)n * CCH + c4) = w;
        *(uint2*)&sN[n * 68 + c4] = w;
    }
    __syncthreads();

    // transpose out: thread owns dword column-pair cp (c=2cp,2cp+1), 8 n values
    const int cp = t >> 3;          // 0..31
    const int ng = (t & 7) * 8;     // 0,8,..,56
    ushort8v o0, o1;
#pragma unroll
    for (int k = 0; k < 8; ++k) {
        unsigned d = *(const unsigned*)&sN[(ng + k) * 68 + cp * 2];
        o0[k] = (unsigned short)(d & 0xffffu);
        o1[k] = (unsigned short)(d >> 16);
    }
    unsigned short* tp = AT + ((size_t)b * CCH + c0) * NPIX + n0;
    *(ushort8v*)(tp + (size_t)(cp * 2)     * NPIX + ng) = o0;
    *(ushort8v*)(tp + (size_t)(cp * 2 + 1) * NPIX + ng) = o1;
}

// ---------------------------------------------------------------------------
// Kernel 1: S_part[s][b][i][j] = sum_{n in split s} A_T[b][i][n] * A_T[b][j][n]
// m97 structure: 128x128 tile, BK=32, global_load_lds width 16, split-K=4.
// ---------------------------------------------------------------------------
__global__ __launch_bounds__(256) void k_ata(const unsigned short* __restrict__ AT,
                                             float* __restrict__ Sp) {
    __shared__ unsigned short sA[128 * 32];
    __shared__ unsigned short sB[128 * 32];
    const int bi = blockIdx.x, bj = blockIdx.y;
    const int b = blockIdx.z & (BATCH - 1), s = blockIdx.z >> 4;
    const unsigned short* pa = AT + ((size_t)b * CCH + bi * 128) * NPIX + s * KSPL;
    const unsigned short* pb = AT + ((size_t)b * CCH + bj * 128) * NPIX + s * KSPL;
    const int tid = threadIdx.x, lane = tid & 63, wave = tid >> 6;
    const int lrow = lane >> 2;            // 0..15
    const int lk   = (lane & 3) * 8;       // 0,8,16,24 shorts

    floatx4 acc[2][8];
#pragma unroll
    for (int tm = 0; tm < 2; ++tm)
#pragma unroll
        for (int tn = 0; tn < 8; ++tn)
            acc[tm][tn] = floatx4{0.f, 0.f, 0.f, 0.f};

    for (int k0 = 0; k0 < KSPL; k0 += 32) {
#pragma unroll
        for (int i = 0; i < 2; ++i) {
            const int r = wave * 32 + i * 16;
            gld16(pa + (size_t)(r + lrow) * NPIX + k0 + lk, &sA[r * 32]);
            gld16(pb + (size_t)(r + lrow) * NPIX + k0 + lk, &sB[r * 32]);
        }
        __syncthreads();

        const int kq = (lane >> 4) * 8;
        bf16x8 af[2], bv[8];
#pragma unroll
        for (int tm = 0; tm < 2; ++tm)
            af[tm] = ld_frag(&sA[(wave * 32 + tm * 16 + (lane & 15)) * 32 + kq]);
#pragma unroll
        for (int tn = 0; tn < 8; ++tn)
            bv[tn] = ld_frag(&sB[(tn * 16 + (lane & 15)) * 32 + kq]);
#pragma unroll
        for (int tm = 0; tm < 2; ++tm)
#pragma unroll
            for (int tn = 0; tn < 8; ++tn)
                acc[tm][tn] = __builtin_amdgcn_mfma_f32_16x16x32_bf16(
                    af[tm], bv[tn], acc[tm][tn], 0, 0, 0);
        __syncthreads();
    }

    float* Sb = Sp + (((size_t)s * BATCH + b) * CCH + bi * 128) * CCH + bj * 128;
#pragma unroll
    for (int tm = 0; tm < 2; ++tm)
#pragma unroll
        for (int tn = 0; tn < 8; ++tn)
#pragma unroll
            for (int r = 0; r < 4; ++r) {
                int irow = wave * 32 + tm * 16 + (lane >> 4) * 4 + r;
                int jcol = tn * 16 + (lane & 15);
                Sb[(size_t)irow * CCH + jcol] = acc[tm][tn][r];
            }
}

// ---------------------------------------------------------------------------
// Kernel 2: sum 4 split partials, row softmax (fp32) -> attn P (bf16)
// ---------------------------------------------------------------------------
__global__ __launch_bounds__(256) void k_softmax(const float* __restrict__ Sp,
                                                 unsigned short* __restrict__ P) {
    __shared__ float red[6];
    const size_t row = blockIdx.x;                     // 0..8191 (b*512 + i)
    const size_t str = (size_t)BATCH * CCH * CCH;      // split stride in floats
    const float* p = Sp + row * CCH;
    const int tid = threadIdx.x, lane = tid & 63, wave = tid >> 6;

    float x0 = p[tid] + p[str + tid] + p[2 * str + tid] + p[3 * str + tid];
    float x1 = p[tid + 256] + p[str + tid + 256] + p[2 * str + tid + 256] + p[3 * str + tid + 256];
    float m = fmaxf(x0, x1);
#pragma unroll
    for (int o = 32; o; o >>= 1) m = fmaxf(m, __shfl_xor(m, o, 64));
    if (lane == 0) red[wave] = m;
    __syncthreads();
    if (tid == 0) red[4] = fmaxf(fmaxf(red[0], red[1]), fmaxf(red[2], red[3]));
    __syncthreads();
    m = red[4];

    float e0 = __expf(x0 - m), e1 = __expf(x1 - m);
    float sum = e0 + e1;
#pragma unroll
    for (int o = 32; o; o >>= 1) sum += __shfl_xor(sum, o, 64);
    if (lane == 0) red[wave] = sum;
    __syncthreads();
    if (tid == 0) red[5] = red[0] + red[1] + red[2] + red[3];
    __syncthreads();
    float inv = 1.0f / red[5];

    P[row * CCH + tid]       = f2bf(e0 * inv);
    P[row * CCH + tid + 256] = f2bf(e1 * inv);
}

// ---------------------------------------------------------------------------
// Kernel 3: out[b][n][i] = gamma * sum_j P[b][i][j]*A_bf[b][n][j] + inp[b][n][i]
// Both operands k(=j)-contiguous bf16 -> global_load_lds staging.
// ---------------------------------------------------------------------------
__global__ __launch_bounds__(256) void k_av(const unsigned short* __restrict__ Abf,
                                            const unsigned short* __restrict__ P,
                                            const float* __restrict__ inp,
                                            const float* __restrict__ gamma,
                                            float* __restrict__ out) {
    __shared__ unsigned short sA[128 * 32];   // [n][j]
    __shared__ unsigned short sB[128 * 32];   // [i][j]
    const int bn = blockIdx.x, bi = blockIdx.y, b = blockIdx.z;
    const unsigned short* pa = Abf + ((size_t)b * NPIX + bn * 128) * CCH;
    const unsigned short* pb = P + ((size_t)b * CCH + bi * 128) * CCH;
    const int tid = threadIdx.x, lane = tid & 63, wave = tid >> 6;
    const int lrow = lane >> 2;
    const int lk   = (lane & 3) * 8;
    const float g = gamma[0];

    floatx4 acc[2][8];
#pragma unroll
    for (int tm = 0; tm < 2; ++tm)
#pragma unroll
        for (int tn = 0; tn < 8; ++tn)
            acc[tm][tn] = floatx4{0.f, 0.f, 0.f, 0.f};

    for (int k0 = 0; k0 < CCH; k0 += 32) {
#pragma unroll
        for (int i = 0; i < 2; ++i) {
            const int r = wave * 32 + i * 16;
            gld16(pa + (size_t)(r + lrow) * CCH + k0 + lk, &sA[r * 32]);
            gld16(pb + (size_t)(r + lrow) * CCH + k0 + lk, &sB[r * 32]);
        }
        __syncthreads();

        const int kq = (lane >> 4) * 8;
        bf16x8 af[2], bv[8];
#pragma unroll
        for (int tm = 0; tm < 2; ++tm)
            af[tm] = ld_frag(&sA[(wave * 32 + tm * 16 + (lane & 15)) * 32 + kq]);
#pragma unroll
        for (int tn = 0; tn < 8; ++tn)
            bv[tn] = ld_frag(&sB[(tn * 16 + (lane & 15)) * 32 + kq]);
#pragma unroll
        for (int tm = 0; tm < 2; ++tm)
#pragma unroll
            for (int tn = 0; tn < 8; ++tn)
                acc[tm][tn] = __builtin_amdgcn_mfma_f32_16x16x32_bf16(
                    af[tm], bv[tn], acc[tm][tn], 0, 0, 0);
        __syncthreads();
    }

    float* Ob = out + ((size_t)b * NPIX + bn * 128) * CCH + bi * 128;
    const float* Ib = inp + ((size_t)b * NPIX + bn * 128) * CCH + bi * 128;
#pragma unroll
    for (int tm = 0; tm < 2; ++tm)
#pragma unroll
        for (int tn = 0; tn < 8; ++tn)
#pragma unroll
            for (int r = 0; r < 4; ++r) {
                int nrow = wave * 32 + tm * 16 + (lane >> 4) * 4 + r;
                int icol = tn * 16 + (lane & 15);
                size_t o = (size_t)nrow * CCH + icol;
                Ob[o] = g * acc[tm][tn][r] + Ib[o];
            }
}

// ---------------------------------------------------------------------------
extern "C" void kernel_launch(void* const* d_in, const int* in_sizes, int n_in,
                              void* d_out, int out_size, void* d_ws, size_t ws_size,
                              hipStream_t stream) {
    const float* inp   = (const float*)d_in[0];
    const float* gamma = (const float*)d_in[1];
    float* out = (float*)d_out;

    // workspace layout (200 MiB total)
    char* ws = (char*)d_ws;
    unsigned short* Abf = (unsigned short*)ws;                       //  64 MiB
    unsigned short* AT  = (unsigned short*)(ws + (size_t)67108864);  //  64 MiB
    float*          Sp  = (float*)(ws + (size_t)134217728);          //  64 MiB (4 splits)
    unsigned short* P   = (unsigned short*)(ws + (size_t)201326592); //   8 MiB

    k_cvt<<<dim3(NPIX / 64, CCH / 64, BATCH), 256, 0, stream>>>(inp, Abf, AT);
    k_ata<<<dim3(4, 4, BATCH * NSPLIT), 256, 0, stream>>>(AT, Sp);
    k_softmax<<<BATCH * CCH, 256, 0, stream>>>(Sp, P);
    k_av<<<dim3(NPIX / 128, CCH / 128, BATCH), 256, 0, stream>>>(Abf, P, inp, gamma, out);
}

// Round 3
// 414.296 us; speedup vs baseline: 1.2826x; 1.1079x over previous
//
#include <hip/hip_runtime.h>

#define BATCH 16
#define NPIX  4096
#define CCH   512
#define NSPLIT 8
#define KSPL  (NPIX / NSPLIT)   // 512
#define NUT   10                // upper-triangular 128x128 tile pairs of 4x4

using bf16x8   = __attribute__((ext_vector_type(8))) __bf16;
using floatx4  = __attribute__((ext_vector_type(4))) float;
using ushort8v = __attribute__((ext_vector_type(8))) unsigned short;
using ushort4v = __attribute__((ext_vector_type(4))) unsigned short;

static __device__ __forceinline__ unsigned short f2bf(float f) {
    unsigned u = __builtin_bit_cast(unsigned, f);
    unsigned r = 0x7fffu + ((u >> 16) & 1u);   // round-to-nearest-even
    return (unsigned short)((u + r) >> 16);
}
static __device__ __forceinline__ float bf2f(unsigned short v) {
    unsigned u = ((unsigned)v) << 16;
    return __builtin_bit_cast(float, u);
}
static __device__ __forceinline__ bf16x8 ld_frag(const unsigned short* p) {
    return __builtin_bit_cast(bf16x8, *(const ushort8v*)p);
}
// async global->LDS, 16B per lane; LDS dest = wave-uniform base + lane*16
static __device__ __forceinline__ void gld16(const unsigned short* g, unsigned short* l) {
    __builtin_amdgcn_global_load_lds(
        (const __attribute__((address_space(1))) void*)g,
        (__attribute__((address_space(3))) void*)l,
        16, 0, 0);
}

// ---------------------------------------------------------------------------
// Kernel 0: fp32 [b][n][c] -> bf16 Abf [b][n][c] AND bf16 AT [b][c][n]
// 64x64 tile; LDS pitch 66 shorts -> conflict-free dword-pair transpose.
// ---------------------------------------------------------------------------
__global__ __launch_bounds__(256) void k_cvt(const float* __restrict__ inp,
                                             unsigned short* __restrict__ Abf,
                                             unsigned short* __restrict__ AT) {
    __shared__ unsigned short sN[64 * 66];
    const int bn = blockIdx.x, bc = blockIdx.y, b = blockIdx.z;
    const int t  = threadIdx.x;
    const int n0 = bn * 64, c0 = bc * 64;
    const float* ip = inp + ((size_t)b * NPIX + n0) * CCH + c0;
    unsigned short* op = Abf + ((size_t)b * NPIX + n0) * CCH + c0;

#pragma unroll
    for (int r = 0; r < 2; ++r) {
        int n  = r * 32 + (t >> 3);
        int c8 = (t & 7) * 8;
        float4 v0 = *(const float4*)(ip + (size_t)n * CCH + c8);
        float4 v1 = *(const float4*)(ip + (size_t)n * CCH + c8 + 4);
        ushort8v w;
        w[0] = f2bf(v0.x); w[1] = f2bf(v0.y); w[2] = f2bf(v0.z); w[3] = f2bf(v0.w);
        w[4] = f2bf(v1.x); w[5] = f2bf(v1.y); w[6] = f2bf(v1.z); w[7] = f2bf(v1.w);
        *(ushort8v*)(op + (size_t)n * CCH + c8) = w;
        *(ushort8v*)&sN[n * 66 + c8] = w;
    }
    __syncthreads();

    const int cp = t >> 3;          // column pair 0..31
    const int ng = (t & 7) * 8;     // n group
    ushort8v o0, o1;
#pragma unroll
    for (int k = 0; k < 8; ++k) {
        unsigned d = *(const unsigned*)&sN[(ng + k) * 66 + cp * 2];
        o0[k] = (unsigned short)(d & 0xffffu);
        o1[k] = (unsigned short)(d >> 16);
    }
    unsigned short* tp = AT + ((size_t)b * CCH + c0) * NPIX + n0;
    *(ushort8v*)(tp + (size_t)(cp * 2)     * NPIX + ng) = o0;
    *(ushort8v*)(tp + (size_t)(cp * 2 + 1) * NPIX + ng) = o1;
}

// ---------------------------------------------------------------------------
// Kernel 1: upper-triangular tile pairs of S = A^T A, split-K = 8.
// Sp tile layout is MFMA-register-packed bf16:
//   elem (row,col) at (((row>>4)*8 + (col>>4))*64 + (row>>2 & 3)*16 + (col&15))*4 + (row&3)
// ---------------------------------------------------------------------------
__global__ __launch_bounds__(256) void k_ata(const unsigned short* __restrict__ AT,
                                             unsigned short* __restrict__ Sp) {
    __shared__ unsigned short sA[128 * 32];
    __shared__ unsigned short sB[128 * 32];
    const int u = blockIdx.x, s = blockIdx.y, b = blockIdx.z;
    const int ti = (u < 4) ? 0 : (u < 7) ? 1 : (u < 9) ? 2 : 3;
    const int u0 = ti * 5 - (ti * (ti + 1)) / 2;   // first u at tj==ti
    const int tj = ti + (u - u0);
    const unsigned short* pa = AT + ((size_t)b * CCH + ti * 128) * NPIX + s * KSPL;
    const unsigned short* pb = AT + ((size_t)b * CCH + tj * 128) * NPIX + s * KSPL;
    const int tid = threadIdx.x, lane = tid & 63, wave = tid >> 6;
    const int lrow = lane >> 2;
    const int lk   = (lane & 3) * 8;

    floatx4 acc[2][8];
#pragma unroll
    for (int tm = 0; tm < 2; ++tm)
#pragma unroll
        for (int tn = 0; tn < 8; ++tn)
            acc[tm][tn] = floatx4{0.f, 0.f, 0.f, 0.f};

    for (int k0 = 0; k0 < KSPL; k0 += 32) {
#pragma unroll
        for (int i = 0; i < 2; ++i) {
            const int r = wave * 32 + i * 16;
            gld16(pa + (size_t)(r + lrow) * NPIX + k0 + lk, &sA[r * 32]);
            gld16(pb + (size_t)(r + lrow) * NPIX + k0 + lk, &sB[r * 32]);
        }
        __syncthreads();

        const int kq = (lane >> 4) * 8;
        bf16x8 af[2], bv[8];
#pragma unroll
        for (int tm = 0; tm < 2; ++tm)
            af[tm] = ld_frag(&sA[(wave * 32 + tm * 16 + (lane & 15)) * 32 + kq]);
#pragma unroll
        for (int tn = 0; tn < 8; ++tn)
            bv[tn] = ld_frag(&sB[(tn * 16 + (lane & 15)) * 32 + kq]);
#pragma unroll
        for (int tm = 0; tm < 2; ++tm)
#pragma unroll
            for (int tn = 0; tn < 8; ++tn)
                acc[tm][tn] = __builtin_amdgcn_mfma_f32_16x16x32_bf16(
                    af[tm], bv[tn], acc[tm][tn], 0, 0, 0);
        __syncthreads();
    }

    // packed epilogue: 8B/lane fully-coalesced stores
    unsigned short* Tb = Sp + ((((size_t)s * BATCH + b) * NUT + u) << 14);
#pragma unroll
    for (int tm = 0; tm < 2; ++tm)
#pragma unroll
        for (int tn = 0; tn < 8; ++tn) {
            ushort4v w;
#pragma unroll
            for (int r = 0; r < 4; ++r) w[r] = f2bf(acc[tm][tn][r]);
            *(ushort4v*)&Tb[((((wave * 2 + tm) * 8 + tn) * 64) + lane) * 4] = w;
        }
}

// ---------------------------------------------------------------------------
// Kernel 2: gather 8 bf16 split-partials from packed upper-tile storage
// (mirroring for lower triangle), fp32 sum, row softmax -> P bf16.
// ---------------------------------------------------------------------------
__global__ __launch_bounds__(256) void k_softmax(const unsigned short* __restrict__ Sp,
                                                 unsigned short* __restrict__ P) {
    __shared__ float red[6];
    const int row = blockIdx.x;            // b*512 + i
    const int b = row >> 9, i = row & 511;
    const int tid = threadIdx.x, lane = tid & 63, wave = tid >> 6;
    const size_t sstr = (size_t)BATCH * NUT * 16384;   // split stride (shorts)

    float x[2];
#pragma unroll
    for (int e = 0; e < 2; ++e) {
        const int j  = tid + e * 256;
        const int ti = i >> 7, tj = j >> 7;
        const int il = i & 127, jl = j & 127;
        const bool sw = ti > tj;
        const int a  = sw ? tj : ti;
        const int cm = sw ? ti : tj;
        const int u  = a * 4 + cm - ((a * (a + 1)) >> 1);
        const int rr = sw ? jl : il;
        const int cc = sw ? il : jl;
        const int off = ((((rr >> 4) * 8 + (cc >> 4)) * 64) +
                         ((rr >> 2) & 3) * 16 + (cc & 15)) * 4 + (rr & 3);
        const size_t base = (((size_t)b * NUT + u) << 14) + off;
        float v = 0.f;
#pragma unroll
        for (int s = 0; s < NSPLIT; ++s) v += bf2f(Sp[base + s * sstr]);
        x[e] = v;
    }

    float m = fmaxf(x[0], x[1]);
#pragma unroll
    for (int o = 32; o; o >>= 1) m = fmaxf(m, __shfl_xor(m, o, 64));
    if (lane == 0) red[wave] = m;
    __syncthreads();
    if (tid == 0) red[4] = fmaxf(fmaxf(red[0], red[1]), fmaxf(red[2], red[3]));
    __syncthreads();
    m = red[4];

    float e0 = __expf(x[0] - m), e1 = __expf(x[1] - m);
    float sum = e0 + e1;
#pragma unroll
    for (int o = 32; o; o >>= 1) sum += __shfl_xor(sum, o, 64);
    if (lane == 0) red[wave] = sum;
    __syncthreads();
    if (tid == 0) red[5] = red[0] + red[1] + red[2] + red[3];
    __syncthreads();
    float inv = 1.0f / red[5];

    P[(size_t)row * CCH + tid]       = f2bf(e0 * inv);
    P[(size_t)row * CCH + tid + 256] = f2bf(e1 * inv);
}

// ---------------------------------------------------------------------------
// Kernel 3: out[b][n][i] = gamma * sum_j P[b][i][j]*Abf[b][n][j] + inp[b][n][i]
// ---------------------------------------------------------------------------
__global__ __launch_bounds__(256) void k_av(const unsigned short* __restrict__ Abf,
                                            const unsigned short* __restrict__ P,
                                            const float* __restrict__ inp,
                                            const float* __restrict__ gamma,
                                            float* __restrict__ out) {
    __shared__ unsigned short sA[128 * 32];   // [n][j]
    __shared__ unsigned short sB[128 * 32];   // [i][j]
    const int bn = blockIdx.x, bi = blockIdx.y, b = blockIdx.z;
    const unsigned short* pa = Abf + ((size_t)b * NPIX + bn * 128) * CCH;
    const unsigned short* pb = P + ((size_t)b * CCH + bi * 128) * CCH;
    const int tid = threadIdx.x, lane = tid & 63, wave = tid >> 6;
    const int lrow = lane >> 2;
    const int lk   = (lane & 3) * 8;
    const float g = gamma[0];

    floatx4 acc[2][8];
#pragma unroll
    for (int tm = 0; tm < 2; ++tm)
#pragma unroll
        for (int tn = 0; tn < 8; ++tn)
            acc[tm][tn] = floatx4{0.f, 0.f, 0.f, 0.f};

    for (int k0 = 0; k0 < CCH; k0 += 32) {
#pragma unroll
        for (int i = 0; i < 2; ++i) {
            const int r = wave * 32 + i * 16;
            gld16(pa + (size_t)(r + lrow) * CCH + k0 + lk, &sA[r * 32]);
            gld16(pb + (size_t)(r + lrow) * CCH + k0 + lk, &sB[r * 32]);
        }
        __syncthreads();

        const int kq = (lane >> 4) * 8;
        bf16x8 af[2], bv[8];
#pragma unroll
        for (int tm = 0; tm < 2; ++tm)
            af[tm] = ld_frag(&sA[(wave * 32 + tm * 16 + (lane & 15)) * 32 + kq]);
#pragma unroll
        for (int tn = 0; tn < 8; ++tn)
            bv[tn] = ld_frag(&sB[(tn * 16 + (lane & 15)) * 32 + kq]);
#pragma unroll
        for (int tm = 0; tm < 2; ++tm)
#pragma unroll
            for (int tn = 0; tn < 8; ++tn)
                acc[tm][tn] = __builtin_amdgcn_mfma_f32_16x16x32_bf16(
                    af[tm], bv[tn], acc[tm][tn], 0, 0, 0);
        __syncthreads();
    }

    float* Ob = out + ((size_t)b * NPIX + bn * 128) * CCH + bi * 128;
    const float* Ib = inp + ((size_t)b * NPIX + bn * 128) * CCH + bi * 128;
#pragma unroll
    for (int tm = 0; tm < 2; ++tm)
#pragma unroll
        for (int tn = 0; tn < 8; ++tn)
#pragma unroll
            for (int r = 0; r < 4; ++r) {
                int nrow = wave * 32 + tm * 16 + (lane >> 4) * 4 + r;
                int icol = tn * 16 + (lane & 15);
                size_t o = (size_t)nrow * CCH + icol;
                Ob[o] = g * acc[tm][tn][r] + Ib[o];
            }
}

// ---------------------------------------------------------------------------
extern "C" void kernel_launch(void* const* d_in, const int* in_sizes, int n_in,
                              void* d_out, int out_size, void* d_ws, size_t ws_size,
                              hipStream_t stream) {
    const float* inp   = (const float*)d_in[0];
    const float* gamma = (const float*)d_in[1];
    float* out = (float*)d_out;

    // workspace: Abf 64 MiB | AT 64 MiB | Sp 40 MiB | P 8 MiB  (~176.5 MiB)
    char* ws = (char*)d_ws;
    unsigned short* Abf = (unsigned short*)ws;
    unsigned short* AT  = (unsigned short*)(ws + (size_t)67108864);
    unsigned short* Sp  = (unsigned short*)(ws + (size_t)134217728);
    unsigned short* P   = (unsigned short*)(ws + (size_t)134217728 + 41943040);

    k_cvt<<<dim3(NPIX / 64, CCH / 64, BATCH), 256, 0, stream>>>(inp, Abf, AT);
    k_ata<<<dim3(NUT, NSPLIT, BATCH), 256, 0, stream>>>(AT, Sp);
    k_softmax<<<BATCH * CCH, 256, 0, stream>>>(Sp, P);
    k_av<<<dim3(NPIX / 128, CCH / 128, BATCH), 256, 0, stream>>>(Abf, P, inp, gamma, out);
}